// Round 1
// baseline (1043.357 us; speedup 1.0000x reference)
//
#include <hip/hip_runtime.h>

typedef _Float16 f16x8 __attribute__((ext_vector_type(8)));
typedef _Float16 f16x4 __attribute__((ext_vector_type(4)));
typedef float    f32x4 __attribute__((ext_vector_type(4)));

#define BM 128
#define BN 128
#define BK 32

#define BM2 256
#define BN2 256
#define BK2 32   // f16 elems per row; row = 64 B = 4 chunks of 16 B

// async global->LDS, 16B per lane. LDS dst must be wave-uniform base + lane*16.
__device__ __forceinline__ void gld16(const void* g, void* l) {
  __builtin_amdgcn_global_load_lds(
      (__attribute__((address_space(1))) void*)const_cast<void*>(g),
      (__attribute__((address_space(3))) void*)l, 16, 0, 0);
}

// Branchless activations from ONE native exp:
//   e = exp(-|v|), e2 = e*e = exp(-2|v|); fast v_rcp for the divides.
// relu / sigmoid / tanh / leaky(0.1) / selu, then min(out, cap).
__device__ __forceinline__ float act_clip(int f, float v, float cap) {
  const float sc = 1.0507009873554805f, al = 1.6732632423543772f;
  const float av = fabsf(v);
  const float e  = __expf(-av);
  const float e2 = e * e;
  const bool  pos = (v >= 0.0f);

  const float r1 = __builtin_amdgcn_rcpf(1.0f + e);
  const float sig = pos ? r1 : e * r1;                 // sigmoid(v)
  float th = (1.0f - e2) * __builtin_amdgcn_rcpf(1.0f + e2);
  th = pos ? th : -th;                                  // tanh(v)
  const float rel = fmaxf(v, 0.0f);
  const float lk  = pos ? v : 0.1f * v;
  const float sel = pos ? sc * v : sc * al * (e - 1.0f);

  float out = rel;
  out = (f == 1) ? sig : out;
  out = (f == 2) ? th  : out;
  out = (f == 3) ? lk  : out;
  out = (f == 4) ? sel : out;
  return fminf(out, cap);
}

// ---------------------------------------------------------------------------
// 256x256 phased kernel for the X-layers (N%256==0, rows%256==0, K%32==0).
// 8 waves (2Mx4N), wave tile 128x64, acc[8][4]. Double-buffered 128 KiB LDS,
// counted vmcnt(8) (never 0 in main loop), raw s_barrier (2/iter), per-K-tile
// compute split into 4 row-group phases with setprio(1) around MFMA clusters.
// T2 swizzle: 16B chunk index XOR (row>>1)&3, applied to the GLOBAL source at
// stage time (LDS dest stays linear for global_load_lds) and to the ds_read
// address — same involution both sides.
// ---------------------------------------------------------------------------
__global__ __launch_bounds__(512, 2) void gemm_split_act_256(
    const _Float16* __restrict__ Ahi, const _Float16* __restrict__ Alo,
    const _Float16* __restrict__ Whi, const _Float16* __restrict__ Wlo,
    const float* __restrict__ bias, const int* __restrict__ fid,
    const float* __restrict__ cap, int N, int K, int nCol, int nRow,
    _Float16* __restrict__ Ohi, _Float16* __restrict__ Olo)
{
  // [buf][plane][row*BK2 + k] : 2*2*16KB per operand = 128 KiB total
  __shared__ _Float16 sA[2][2][BM2 * BK2];
  __shared__ _Float16 sB[2][2][BN2 * BK2];

  const int tid  = threadIdx.x;
  const int lane = tid & 63;
  const int wave = tid >> 6;
  const int wm = (wave >> 2) * 128;     // wave row offset (0 or 128)
  const int wn = (wave & 3) * 64;       // wave col offset
  const int ml = lane & 15;
  const int q  = lane >> 4;

  int rb, cb;
  if ((nRow & 7) == 0) {
    const int id = blockIdx.x;
    const int xcd = id & 7, slot = id >> 3;
    cb = slot % nCol;
    rb = (slot / nCol) * 8 + xcd;
  } else {
    cb = blockIdx.x % nCol;
    rb = blockIdx.x / nCol;
  }

  const long row0 = (long)rb * BM2;
  const int  col0 = cb * BN2;

  // staging: thread covers row srow (and srow+128 on round 2), 16B chunk (tid&3).
  // Global source chunk is pre-swizzled: c_global = c_lds ^ ((srow>>1)&3).
  // Note ((srow+128)>>1)&3 == ((srow>>1)&3), so one xor serves both rounds.
  const int srow = tid >> 2;                       // 0..127
  const int sx   = (srow >> 1) & 3;
  const int scol = (((tid & 3) ^ sx)) * 8;         // f16 elems
  const _Float16* gAh = Ahi + (row0 + srow) * (long)K + scol;
  const _Float16* gAl = Alo + (row0 + srow) * (long)K + scol;
  const _Float16* gBh = Whi + (long)(col0 + srow) * K + scol;
  const _Float16* gBl = Wlo + (long)(col0 + srow) * K + scol;
  const int ldst = tid * 8;                        // linear LDS dst (f16 units)

  f32x4 acc[8][4] = {};
  const int nt = K / BK2;

  auto STAGE = [&](int buf, long k0) {             // 8 gld16 per thread/wave
    gld16(gAh + k0,                 &sA[buf][0][ldst]);
    gld16(gAh + (long)128 * K + k0, &sA[buf][0][128 * BK2 + ldst]);
    gld16(gAl + k0,                 &sA[buf][1][ldst]);
    gld16(gAl + (long)128 * K + k0, &sA[buf][1][128 * BK2 + ldst]);
    gld16(gBh + k0,                 &sB[buf][0][ldst]);
    gld16(gBh + (long)128 * K + k0, &sB[buf][0][128 * BK2 + ldst]);
    gld16(gBl + k0,                 &sB[buf][1][ldst]);
    gld16(gBl + (long)128 * K + k0, &sB[buf][1][128 * BK2 + ldst]);
  };

  auto COMPUTE = [&](int cur) {
    // B fragments once per K-tile (reused by all 4 phases)
    f16x8 bh[4], bl[4];
#pragma unroll
    for (int j = 0; j < 4; ++j) {
      const int row = wn + j * 16 + ml;
      const int c = (q ^ ((row >> 1) & 3)) * 8;
      bh[j] = *(const f16x8*)&sB[cur][0][row * BK2 + c];
      bl[j] = *(const f16x8*)&sB[cur][1][row * BK2 + c];
    }
#pragma unroll
    for (int p = 0; p < 4; ++p) {                  // 4 row-group phases
      f16x8 ah[2], al[2];
#pragma unroll
      for (int i = 0; i < 2; ++i) {
        const int row = wm + (p * 2 + i) * 16 + ml;
        const int c = (q ^ ((row >> 1) & 3)) * 8;
        ah[i] = *(const f16x8*)&sA[cur][0][row * BK2 + c];
        al[i] = *(const f16x8*)&sA[cur][1][row * BK2 + c];
      }
      __builtin_amdgcn_s_setprio(1);
#pragma unroll
      for (int i = 0; i < 2; ++i)
#pragma unroll
        for (int j = 0; j < 4; ++j) {
          acc[p*2+i][j] = __builtin_amdgcn_mfma_f32_16x16x32_f16(ah[i], bh[j], acc[p*2+i][j], 0, 0, 0);
          acc[p*2+i][j] = __builtin_amdgcn_mfma_f32_16x16x32_f16(ah[i], bl[j], acc[p*2+i][j], 0, 0, 0);
          acc[p*2+i][j] = __builtin_amdgcn_mfma_f32_16x16x32_f16(al[i], bh[j], acc[p*2+i][j], 0, 0, 0);
        }
      __builtin_amdgcn_s_setprio(0);
    }
  };

  STAGE(0, 0);
  if (nt > 1) STAGE(1, BK2);

  int t = 0;
  for (; t + 1 < nt; ++t) {
    // wait for tile t only; tile t+1's 8 loads stay in flight across the barrier
    asm volatile("s_waitcnt vmcnt(8)" ::: "memory");
    __builtin_amdgcn_s_barrier();
    asm volatile("" ::: "memory");
    COMPUTE(t & 1);
    asm volatile("" ::: "memory");
    __builtin_amdgcn_s_barrier();                  // all waves done reading buf
    if (t + 2 < nt) STAGE(t & 1, (long)(t + 2) * BK2);
  }
  asm volatile("s_waitcnt vmcnt(0)" ::: "memory"); // drain for the last tile
  __builtin_amdgcn_s_barrier();
  asm volatile("" ::: "memory");
  COMPUTE(t & 1);

  // epilogue: C/D layout col = lane&15, row = (lane>>4)*4 + reg
#pragma unroll
  for (int j = 0; j < 4; ++j) {
    const int col = col0 + wn + j * 16 + ml;
    const float bj = bias[col];
    const int   fj = fid[col];
    const float cj = cap[col];
#pragma unroll
    for (int i = 0; i < 8; ++i) {
      const long rbase = row0 + wm + i * 16 + q * 4;
#pragma unroll
      for (int r = 0; r < 4; ++r) {
        float v = act_clip(fj, acc[i][j][r] + bj, cj);
        const long idx = (rbase + r) * (long)N + col;
        _Float16 h = (_Float16)v;
        Ohi[idx] = h;
        Olo[idx] = (_Float16)(v - (float)h);
      }
    }
  }
}

// ---------------------------------------------------------------------------
// Proven 128x128 kernel (kept for the D_OUT=128 layer and as generic fallback)
// ---------------------------------------------------------------------------
__global__ __launch_bounds__(256, 4) void gemm_split_act(
    const _Float16* __restrict__ Ahi, const _Float16* __restrict__ Alo,
    const _Float16* __restrict__ Whi, const _Float16* __restrict__ Wlo,
    const float* __restrict__ bias, const int* __restrict__ fid,
    const float* __restrict__ cap, int N, int K, int nCol, int nRow,
    _Float16* __restrict__ Ohi, _Float16* __restrict__ Olo,
    float* __restrict__ Ofin)
{
  __shared__ _Float16 sA[2][BM * BK];   // [hi/lo][row*BK + k], rows = batch
  __shared__ _Float16 sB[2][BN * BK];   // [hi/lo][row*BK + k], rows = out-feature

  const int tid  = threadIdx.x;
  const int lane = tid & 63;
  const int wave = tid >> 6;
  const int wm = (wave >> 1) * 64;
  const int wn = (wave & 1) * 64;
  const int ml = lane & 15;
  const int q  = lane >> 4;

  int rb, cb;
  if ((nRow & 7) == 0) {
    const int id = blockIdx.x;
    const int xcd = id & 7, slot = id >> 3;
    cb = slot % nCol;
    rb = (slot / nCol) * 8 + xcd;
  } else {
    cb = blockIdx.x % nCol;
    rb = blockIdx.x / nCol;
  }

  const long row0 = (long)rb * BM;
  const int  col0 = cb * BN;

  const int srow = tid >> 2;
  const int scol = (tid & 3) * 8;
  const _Float16* gAh = Ahi + (row0 + srow) * (long)K + scol;
  const _Float16* gAl = Alo + (row0 + srow) * (long)K + scol;
  const _Float16* gBh = Whi + (long)(col0 + srow) * K + scol;
  const _Float16* gBl = Wlo + (long)(col0 + srow) * K + scol;

  f32x4 acc[4][4] = {};

  for (int k0 = 0; k0 < K; k0 += BK) {
    gld16(gAh + k0,                &sA[0][tid * 8]);
    gld16(gAh + (long)64 * K + k0, &sA[0][64 * BK + tid * 8]);
    gld16(gAl + k0,                &sA[1][tid * 8]);
    gld16(gAl + (long)64 * K + k0, &sA[1][64 * BK + tid * 8]);
    gld16(gBh + k0,                &sB[0][tid * 8]);
    gld16(gBh + (long)64 * K + k0, &sB[0][64 * BK + tid * 8]);
    gld16(gBl + k0,                &sB[1][tid * 8]);
    gld16(gBl + (long)64 * K + k0, &sB[1][64 * BK + tid * 8]);
    __syncthreads();

    f16x8 ah[4], al[4], bh[4], bl[4];
#pragma unroll
    for (int i = 0; i < 4; i++) {
      ah[i] = *(const f16x8*)&sA[0][(wm + i * 16 + ml) * BK + q * 8];
      al[i] = *(const f16x8*)&sA[1][(wm + i * 16 + ml) * BK + q * 8];
    }
#pragma unroll
    for (int j = 0; j < 4; j++) {
      bh[j] = *(const f16x8*)&sB[0][(wn + j * 16 + ml) * BK + q * 8];
      bl[j] = *(const f16x8*)&sB[1][(wn + j * 16 + ml) * BK + q * 8];
    }
#pragma unroll
    for (int i = 0; i < 4; i++)
#pragma unroll
      for (int j = 0; j < 4; j++) {
        acc[i][j] = __builtin_amdgcn_mfma_f32_16x16x32_f16(ah[i], bh[j], acc[i][j], 0, 0, 0);
        acc[i][j] = __builtin_amdgcn_mfma_f32_16x16x32_f16(ah[i], bl[j], acc[i][j], 0, 0, 0);
        acc[i][j] = __builtin_amdgcn_mfma_f32_16x16x32_f16(al[i], bh[j], acc[i][j], 0, 0, 0);
      }
    __syncthreads();
  }

#pragma unroll
  for (int j = 0; j < 4; j++) {
    const int col = col0 + wn + j * 16 + ml;
    const float bj = bias[col];
    const int   fj = fid[col];
    const float cj = cap[col];
#pragma unroll
    for (int i = 0; i < 4; i++) {
      const long rbase = row0 + wm + i * 16 + q * 4;
#pragma unroll
      for (int r = 0; r < 4; r++) {
        float v = act_clip(fj, acc[i][j][r] + bj, cj);
        const long idx = (rbase + r) * (long)N + col;
        if (Ofin) {
          Ofin[idx] = v;
        } else {
          _Float16 h = (_Float16)v;
          Ohi[idx] = h;
          Olo[idx] = (_Float16)(v - (float)h);
        }
      }
    }
  }
}

// fp32 -> (hi,lo) f16 split planes, 4 elems/thread
__global__ void split_f32(const float* __restrict__ x, _Float16* __restrict__ hi,
                          _Float16* __restrict__ lo, long n)
{
  long i = ((long)blockIdx.x * 256 + threadIdx.x) * 4;
  if (i >= n) return;
  float4 v = *(const float4*)(x + i);
  f16x4 h, l;
  h[0] = (_Float16)v.x; l[0] = (_Float16)(v.x - (float)h[0]);
  h[1] = (_Float16)v.y; l[1] = (_Float16)(v.y - (float)h[1]);
  h[2] = (_Float16)v.z; l[2] = (_Float16)(v.z - (float)h[2]);
  h[3] = (_Float16)v.w; l[3] = (_Float16)(v.w - (float)h[3]);
  *(f16x4*)(hi + i) = h;
  *(f16x4*)(lo + i) = l;
}

extern "C" void kernel_launch(void* const* d_in, const int* in_sizes, int n_in,
                              void* d_out, int out_size, void* d_ws, size_t ws_size,
                              hipStream_t stream)
{
  const float* input = (const float*)d_in[0];
  const float* W_in  = (const float*)d_in[1];
  const float* b_in  = (const float*)d_in[2];
  const float* W_h   = (const float*)d_in[3];
  const float* b_h   = (const float*)d_in[4];
  const float* W_out = (const float*)d_in[5];
  const float* b_out = (const float*)d_in[6];
  const float* m_in  = (const float*)d_in[7];
  const float* m_h   = (const float*)d_in[8];
  const float* m_out = (const float*)d_in[9];
  const int* fid_in  = (const int*)d_in[10];
  const int* fid_h   = (const int*)d_in[11];
  const int* fid_out = (const int*)d_in[12];

  const int X     = in_sizes[2];                 // 512
  const int D_IN  = in_sizes[1] / X;             // 512
  const int Z     = in_sizes[3] / (X * X);       // 4
  const int D_OUT = in_sizes[6];                 // 128
  const long B    = (long)in_sizes[0] / D_IN;    // 65536

  const long w_elems = (long)X * D_IN + (long)Z * X * X + (long)D_OUT * X;
  _Float16* Whi = (_Float16*)d_ws;
  _Float16* Wlo = Whi + w_elems;
  char* actbase = (char*)(Wlo + w_elems);

  // row chunking so 2 ping-pong activation buffers (hi+lo f16 each) fit in ws;
  // align to 256 so the 256-tile kernel is usable for every chunk
  size_t wbytes = 4 * (size_t)w_elems;
  size_t avail  = ws_size > wbytes ? ws_size - wbytes : 0;
  long R = (long)(avail / (8 * (size_t)X));
  R = (R / 256) * 256;
  if (R > B) R = B;
  if (R < BM) R = BM;

  _Float16* bufhi[2];
  _Float16* buflo[2];
  bufhi[0] = (_Float16*)actbase;
  buflo[0] = bufhi[0] + R * (long)X;
  bufhi[1] = buflo[0] + R * (long)X;
  buflo[1] = bufhi[1] + R * (long)X;

  // split weights once per call
  {
    long n0 = (long)X * D_IN;
    long n1 = (long)Z * X * X;
    long n2 = (long)D_OUT * X;
    split_f32<<<(int)((n0 / 4 + 255) / 256), 256, 0, stream>>>(W_in, Whi, Wlo, n0);
    split_f32<<<(int)((n1 / 4 + 255) / 256), 256, 0, stream>>>(W_h, Whi + n0, Wlo + n0, n1);
    split_f32<<<(int)((n2 / 4 + 255) / 256), 256, 0, stream>>>(W_out, Whi + n0 + n1, Wlo + n0 + n1, n2);
  }

  const long woff_h   = (long)X * D_IN;
  const long woff_out = woff_h + (long)Z * X * X;

  for (long r0 = 0; r0 < B; r0 += R) {
    const long rows = (B - r0 < R) ? (B - r0) : R;

    // input chunk -> split planes
    {
      long n = rows * (long)D_IN;
      split_f32<<<(int)((n / 4 + 255) / 256), 256, 0, stream>>>(input + r0 * D_IN, bufhi[0], buflo[0], n);
    }

    const bool big = (rows % 256 == 0) && (X % 256 == 0) &&
                     (D_IN % 32 == 0) && (X % 32 == 0);
    int cur;
    if (big) {
      const int nR2 = (int)(rows / 256);
      const int nC2 = X / 256;
      dim3 g2((unsigned)(nR2 * nC2));
      gemm_split_act_256<<<g2, 512, 0, stream>>>(bufhi[0], buflo[0], Whi, Wlo,
          b_in, fid_in, m_in, X, D_IN, nC2, nR2, bufhi[1], buflo[1]);
      cur = 1;
      for (int i = 0; i < Z; i++) {
        const _Float16* wh = Whi + woff_h + (long)i * X * X;
        const _Float16* wl = Wlo + woff_h + (long)i * X * X;
        gemm_split_act_256<<<g2, 512, 0, stream>>>(bufhi[cur], buflo[cur], wh, wl,
            b_h + (long)i * X, fid_h + (long)i * X, m_h + (long)i * X, X, X,
            nC2, nR2, bufhi[1 - cur], buflo[1 - cur]);
        cur ^= 1;
      }
    } else {
      const int nRow  = (int)(rows / BM);
      const int nColH = X / BN;
      dim3 gridH((unsigned)(nRow * nColH));
      gemm_split_act<<<gridH, 256, 0, stream>>>(bufhi[0], buflo[0], Whi, Wlo,
          b_in, fid_in, m_in, X, D_IN, nColH, nRow, bufhi[1], buflo[1], nullptr);
      cur = 1;
      for (int i = 0; i < Z; i++) {
        const _Float16* wh = Whi + woff_h + (long)i * X * X;
        const _Float16* wl = Wlo + woff_h + (long)i * X * X;
        gemm_split_act<<<gridH, 256, 0, stream>>>(bufhi[cur], buflo[cur], wh, wl,
            b_h + (long)i * X, fid_h + (long)i * X, m_h + (long)i * X, X, X,
            nColH, nRow, bufhi[1 - cur], buflo[1 - cur], nullptr);
        cur ^= 1;
      }
    }
    const int nRowO = (int)(rows / BM);
    const int nColO = D_OUT / BN;
    dim3 gridO((unsigned)(nRowO * nColO));
    gemm_split_act<<<gridO, 256, 0, stream>>>(bufhi[cur], buflo[cur],
        Whi + woff_out, Wlo + woff_out, b_out, fid_out, m_out, D_OUT, X,
        nColO, nRowO, nullptr, nullptr, (float*)d_out + r0 * (long)D_OUT);
  }
}

// Round 3
// 996.095 us; speedup vs baseline: 1.0474x; 1.0474x over previous
//
#include <hip/hip_runtime.h>

typedef _Float16 f16x8 __attribute__((ext_vector_type(8)));
typedef _Float16 f16x4 __attribute__((ext_vector_type(4)));
typedef float    f32x4 __attribute__((ext_vector_type(4)));

#define BM 128
#define BN 128
#define BK 32

// async global->LDS, 16B per lane. LDS dst must be wave-uniform base + lane*16.
__device__ __forceinline__ void gld16(const void* g, void* l) {
  __builtin_amdgcn_global_load_lds(
      (__attribute__((address_space(1))) void*)const_cast<void*>(g),
      (__attribute__((address_space(3))) void*)l, 16, 0, 0);
}

// Branchless activations from ONE native exp:
//   e = exp(-|v|), e2 = e*e = exp(-2|v|); fast v_rcp for the divides.
// relu / sigmoid / tanh / leaky(0.1) / selu, then min(out, cap).
__device__ __forceinline__ float act_clip(int f, float v, float cap) {
  const float sc = 1.0507009873554805f, al = 1.6732632423543772f;
  const float av = fabsf(v);
  const float e  = __expf(-av);
  const float e2 = e * e;
  const bool  pos = (v >= 0.0f);

  const float r1 = __builtin_amdgcn_rcpf(1.0f + e);
  const float sig = pos ? r1 : e * r1;                 // sigmoid(v)
  float th = (1.0f - e2) * __builtin_amdgcn_rcpf(1.0f + e2);
  th = pos ? th : -th;                                  // tanh(v)
  const float rel = fmaxf(v, 0.0f);
  const float lk  = pos ? v : 0.1f * v;
  const float sel = pos ? sc * v : sc * al * (e - 1.0f);

  float out = rel;
  out = (f == 1) ? sig : out;
  out = (f == 2) ? th  : out;
  out = (f == 3) ? lk  : out;
  out = (f == 4) ? sel : out;
  return fminf(out, cap);
}

// C[M,N] = A[M,K] @ W[N,K]^T + bias, then per-column activation+clip.
// A and W as f16 (hi,lo) split planes; fp32 accumulate via 3 MFMA products.
// NOTE (R2 post-mortem): lo planes are REQUIRED everywhere — this network
// amplifies early-layer error by ~sqrt(X*p)=16x per layer; dropping the
// layer-0 A-lo plane blew absmax from 0.25 to 12.2.
//
// LDS bank-conflict fix (hardware-verified in R1: conflicts 8.4M -> 0,
// bit-exact): row stride is 64 B = 4 x 16 B chunks; naive frag reads put
// 8 lanes on the same 4-bank group (8-way conflict). XOR-swizzle the chunk
// index with (row>>1)&3, BOTH sides (rule #21):
//   - staging: thread (srow, c) loads GLOBAL chunk c ^ ((srow>>1)&3) into
//     linear LDS chunk c (global_load_lds needs a linear dest);
//   - read:    global chunk q of row r sits at LDS chunk q ^ ((r>>1)&3).
// For frag reads row = {wm|wn} + i*16 + ml where wm/wn + i*16 is even with
// half == 0 mod 4, so (row>>1)&3 == (ml>>1)&3 (lane-constant). Lanes then
// cover all 8 (row-parity x chunk) 4-bank groups -> 2 lanes/bank = free.
//
// 1D grid with XCD swizzle: id = xcd + 8*(c + nCol*g), r = 8g+xcd ->
// each XCD runs all col-blocks of one row-group back-to-back (A-tile stays
// in its L2) and W tiles (1 MB/layer) stay L2-resident across row-groups.
__global__ __launch_bounds__(256, 4) void gemm_split_act(
    const _Float16* __restrict__ Ahi, const _Float16* __restrict__ Alo,
    const _Float16* __restrict__ Whi, const _Float16* __restrict__ Wlo,
    const float* __restrict__ bias, const int* __restrict__ fid,
    const float* __restrict__ cap, int N, int K, int nCol, int nRow,
    _Float16* __restrict__ Ohi, _Float16* __restrict__ Olo,
    float* __restrict__ Ofin)
{
  __shared__ _Float16 sA[2][BM * BK];   // [hi/lo][row*BK + k], rows = batch
  __shared__ _Float16 sB[2][BN * BK];   // [hi/lo][row*BK + k], rows = out-feature

  const int tid  = threadIdx.x;
  const int lane = tid & 63;
  const int wave = tid >> 6;
  const int wm = (wave >> 1) * 64;      // wave's row offset in 128x128 tile
  const int wn = (wave & 1) * 64;       // wave's col offset
  const int ml = lane & 15;
  const int q  = lane >> 4;

  int rb, cb;
  if ((nRow & 7) == 0) {
    const int id = blockIdx.x;
    const int xcd = id & 7, slot = id >> 3;
    cb = slot % nCol;
    rb = (slot / nCol) * 8 + xcd;
  } else {
    cb = blockIdx.x % nCol;
    rb = blockIdx.x / nCol;
  }

  const long row0 = (long)rb * BM;
  const int  col0 = cb * BN;

  // staging: thread covers global rows (tid>>2) and 64+(tid>>2), 16B chunk (tid&3).
  // Global chunk pre-swizzled; note ((srow+64)>>1)&3 == ((srow>>1)&3).
  const int srow = tid >> 2;
  const int sx   = (srow >> 1) & 3;
  const int scol = ((tid & 3) ^ sx) * 8;          // f16 elements
  const _Float16* gAh = Ahi + (row0 + srow) * (long)K + scol;
  const _Float16* gAl = Alo + (row0 + srow) * (long)K + scol;
  const _Float16* gBh = Whi + (long)(col0 + srow) * K + scol;
  const _Float16* gBl = Wlo + (long)(col0 + srow) * K + scol;

  // read-side swizzled chunk (lane-constant, see header comment)
  const int cx = (q ^ ((ml >> 1) & 3)) * 8;       // f16 elements

  f32x4 acc[4][4] = {};

  for (int k0 = 0; k0 < K; k0 += BK) {
    gld16(gAh + k0,                &sA[0][tid * 8]);
    gld16(gAh + (long)64 * K + k0, &sA[0][64 * BK + tid * 8]);
    gld16(gAl + k0,                &sA[1][tid * 8]);
    gld16(gAl + (long)64 * K + k0, &sA[1][64 * BK + tid * 8]);
    gld16(gBh + k0,                &sB[0][tid * 8]);
    gld16(gBh + (long)64 * K + k0, &sB[0][64 * BK + tid * 8]);
    gld16(gBl + k0,                &sB[1][tid * 8]);
    gld16(gBl + (long)64 * K + k0, &sB[1][64 * BK + tid * 8]);
    __syncthreads();   // drains vmcnt: staging complete

    f16x8 ah[4], al[4], bh[4], bl[4];
#pragma unroll
    for (int i = 0; i < 4; i++) {
      ah[i] = *(const f16x8*)&sA[0][(wm + i * 16 + ml) * BK + cx];
      al[i] = *(const f16x8*)&sA[1][(wm + i * 16 + ml) * BK + cx];
    }
#pragma unroll
    for (int j = 0; j < 4; j++) {
      bh[j] = *(const f16x8*)&sB[0][(wn + j * 16 + ml) * BK + cx];
      bl[j] = *(const f16x8*)&sB[1][(wn + j * 16 + ml) * BK + cx];
    }
#pragma unroll
    for (int i = 0; i < 4; i++)
#pragma unroll
      for (int j = 0; j < 4; j++) {
        acc[i][j] = __builtin_amdgcn_mfma_f32_16x16x32_f16(ah[i], bh[j], acc[i][j], 0, 0, 0);
        acc[i][j] = __builtin_amdgcn_mfma_f32_16x16x32_f16(ah[i], bl[j], acc[i][j], 0, 0, 0);
        acc[i][j] = __builtin_amdgcn_mfma_f32_16x16x32_f16(al[i], bh[j], acc[i][j], 0, 0, 0);
      }
    __syncthreads();   // all frag reads done before next staging overwrites
  }

  // epilogue: C/D layout col = lane&15, row = (lane>>4)*4 + reg
#pragma unroll
  for (int j = 0; j < 4; j++) {
    const int col = col0 + wn + j * 16 + ml;
    const float bj = bias[col];
    const int   fj = fid[col];
    const float cj = cap[col];
#pragma unroll
    for (int i = 0; i < 4; i++) {
      const long rbase = row0 + wm + i * 16 + q * 4;
#pragma unroll
      for (int r = 0; r < 4; r++) {
        float v = act_clip(fj, acc[i][j][r] + bj, cj);
        const long idx = (rbase + r) * (long)N + col;
        if (Ofin) {
          Ofin[idx] = v;
        } else {
          _Float16 h = (_Float16)v;
          Ohi[idx] = h;
          Olo[idx] = (_Float16)(v - (float)h);
        }
      }
    }
  }
}

// fp32 -> (hi,lo) f16 split planes, 4 elems/thread
__global__ void split_f32(const float* __restrict__ x, _Float16* __restrict__ hi,
                          _Float16* __restrict__ lo, long n)
{
  long i = ((long)blockIdx.x * 256 + threadIdx.x) * 4;
  if (i >= n) return;
  float4 v = *(const float4*)(x + i);
  f16x4 h, l;
  h[0] = (_Float16)v.x; l[0] = (_Float16)(v.x - (float)h[0]);
  h[1] = (_Float16)v.y; l[1] = (_Float16)(v.y - (float)h[1]);
  h[2] = (_Float16)v.z; l[2] = (_Float16)(v.z - (float)h[2]);
  h[3] = (_Float16)v.w; l[3] = (_Float16)(v.w - (float)h[3]);
  *(f16x4*)(hi + i) = h;
  *(f16x4*)(lo + i) = l;
}

extern "C" void kernel_launch(void* const* d_in, const int* in_sizes, int n_in,
                              void* d_out, int out_size, void* d_ws, size_t ws_size,
                              hipStream_t stream)
{
  const float* input = (const float*)d_in[0];
  const float* W_in  = (const float*)d_in[1];
  const float* b_in  = (const float*)d_in[2];
  const float* W_h   = (const float*)d_in[3];
  const float* b_h   = (const float*)d_in[4];
  const float* W_out = (const float*)d_in[5];
  const float* b_out = (const float*)d_in[6];
  const float* m_in  = (const float*)d_in[7];
  const float* m_h   = (const float*)d_in[8];
  const float* m_out = (const float*)d_in[9];
  const int* fid_in  = (const int*)d_in[10];
  const int* fid_h   = (const int*)d_in[11];
  const int* fid_out = (const int*)d_in[12];

  const int X     = in_sizes[2];                 // 512
  const int D_IN  = in_sizes[1] / X;             // 512
  const int Z     = in_sizes[3] / (X * X);       // 4
  const int D_OUT = in_sizes[6];                 // 128
  const long B    = (long)in_sizes[0] / D_IN;    // 65536

  const long w_elems = (long)X * D_IN + (long)Z * X * X + (long)D_OUT * X;
  _Float16* Whi = (_Float16*)d_ws;
  _Float16* Wlo = Whi + w_elems;
  char* actbase = (char*)(Wlo + w_elems);

  // row chunking so 2 ping-pong activation buffers (hi+lo f16 each) fit in ws
  size_t wbytes = 4 * (size_t)w_elems;
  size_t avail  = ws_size > wbytes ? ws_size - wbytes : 0;
  long R = (long)(avail / (8 * (size_t)X));
  R = (R / BM) * BM;
  if (R > B) R = B;
  if (R < BM) R = BM;

  _Float16* bufhi[2];
  _Float16* buflo[2];
  bufhi[0] = (_Float16*)actbase;
  buflo[0] = bufhi[0] + R * (long)X;
  bufhi[1] = buflo[0] + R * (long)X;
  buflo[1] = bufhi[1] + R * (long)X;

  // split weights once per call
  {
    long n0 = (long)X * D_IN;
    long n1 = (long)Z * X * X;
    long n2 = (long)D_OUT * X;
    split_f32<<<(int)((n0 / 4 + 255) / 256), 256, 0, stream>>>(W_in, Whi, Wlo, n0);
    split_f32<<<(int)((n1 / 4 + 255) / 256), 256, 0, stream>>>(W_h, Whi + n0, Wlo + n0, n1);
    split_f32<<<(int)((n2 / 4 + 255) / 256), 256, 0, stream>>>(W_out, Whi + n0 + n1, Wlo + n0 + n1, n2);
  }

  const long woff_h   = (long)X * D_IN;
  const long woff_out = woff_h + (long)Z * X * X;

  for (long r0 = 0; r0 < B; r0 += R) {
    const long rows = (B - r0 < R) ? (B - r0) : R;

    // input chunk -> split planes (both: lo is load-bearing, see R2 note)
    {
      long n = rows * (long)D_IN;
      split_f32<<<(int)((n / 4 + 255) / 256), 256, 0, stream>>>(input + r0 * D_IN, bufhi[0], buflo[0], n);
    }

    const int nRow  = (int)(rows / BM);
    const int nColH = X / BN;
    dim3 gridH((unsigned)(nRow * nColH));
    // layer 0: [rows, D_IN] x W_in[X, D_IN]^T
    gemm_split_act<<<gridH, 256, 0, stream>>>(bufhi[0], buflo[0], Whi, Wlo,
        b_in, fid_in, m_in, X, D_IN, nColH, nRow, bufhi[1], buflo[1], nullptr);
    int cur = 1;
    for (int i = 0; i < Z; i++) {
      const _Float16* wh = Whi + woff_h + (long)i * X * X;
      const _Float16* wl = Wlo + woff_h + (long)i * X * X;
      gemm_split_act<<<gridH, 256, 0, stream>>>(bufhi[cur], buflo[cur], wh, wl,
          b_h + (long)i * X, fid_h + (long)i * X, m_h + (long)i * X, X, X,
          nColH, nRow, bufhi[1 - cur], buflo[1 - cur], nullptr);
      cur ^= 1;
    }
    const int nColO = D_OUT / BN;
    dim3 gridO((unsigned)(nRow * nColO));
    gemm_split_act<<<gridO, 256, 0, stream>>>(bufhi[cur], buflo[cur],
        Whi + woff_out, Wlo + woff_out, b_out, fid_out, m_out, D_OUT, X,
        nColO, nRow, nullptr, nullptr, (float*)d_out + r0 * (long)D_OUT);
  }
}